// Round 5
// baseline (102.361 us; speedup 1.0000x reference)
//
#include <hip/hip_runtime.h>
#include <hip/hip_bf16.h>

#define NROWS 262144
#define B0 2048            // k0 blocks (Q colsum)
#define B1 512             // k1 blocks
#define RPB 512            // rows per k1 block (8 chunks of 64)
// exp(x*0.125) == exp2(x * 0.125*log2(e))
#define CL 0.18033688011112042f

typedef __attribute__((ext_vector_type(8))) short s8v;   // 8 bf16 (4 VGPRs)
typedef __attribute__((ext_vector_type(4))) float f4v;   // MFMA acc / float4

__device__ __forceinline__ ushort f2bf(float x) {        // RNE float->bf16 bits
    unsigned u = __float_as_uint(x);
    u += 0x7FFF + ((u >> 16) & 1);
    return (ushort)(u >> 16);
}

// sum over each contiguous 16-lane group via DPP (VALU pipe, no DS)
__device__ __forceinline__ float dpp_red16(float x) {
    int t;
    t = __builtin_amdgcn_update_dpp(0, __float_as_int(x), 0xB1,  0xF, 0xF, true);
    x += __int_as_float(t);
    t = __builtin_amdgcn_update_dpp(0, __float_as_int(x), 0x4E,  0xF, 0xF, true);
    x += __int_as_float(t);
    t = __builtin_amdgcn_update_dpp(0, __float_as_int(x), 0x141, 0xF, 0xF, true);
    x += __int_as_float(t);
    t = __builtin_amdgcn_update_dpp(0, __float_as_int(x), 0x140, 0xF, 0xF, true);
    x += __int_as_float(t);
    return x;
}

// async global->LDS DMA, 16B/lane. LDS dest = wave-uniform base + lane*16.
__device__ __forceinline__ void dma16(const float* g, float* l) {
    __builtin_amdgcn_global_load_lds(
        (const __attribute__((address_space(1))) unsigned int*)g,
        (__attribute__((address_space(3))) unsigned int*)l, 16, 0, 0);
}

// K0: partial column-sums of exp2(Q*CL). Thread's col-group is fixed
// (total threads % 16 == 0), so partials stay in 4 registers.
__global__ __launch_bounds__(256) void k0_qsum(const float* __restrict__ Q,
                                               float* __restrict__ q_part) { // [B0][64]
    const int tid  = threadIdx.x;
    const int lane = tid & 63;
    const int wid  = tid >> 6;
    const int t    = blockIdx.x * 256 + tid;      // 524288 threads
    const f4v* q4  = (const f4v*)Q;
    float a0 = 0.f, a1 = 0.f, a2 = 0.f, a3 = 0.f;
#pragma unroll 4
    for (int f = t; f < NROWS * 16; f += B0 * 256) {
        f4v v = q4[f];
        a0 += exp2f(v[0] * CL); a1 += exp2f(v[1] * CL);
        a2 += exp2f(v[2] * CL); a3 += exp2f(v[3] * CL);
    }
    // lanes l, l^16, l^32, l^48 share the same col-group: sum them
    a0 += __shfl_xor(a0, 16); a0 += __shfl_xor(a0, 32);
    a1 += __shfl_xor(a1, 16); a1 += __shfl_xor(a1, 32);
    a2 += __shfl_xor(a2, 16); a2 += __shfl_xor(a2, 32);
    a3 += __shfl_xor(a3, 16); a3 += __shfl_xor(a3, 32);
    __shared__ float part[4][64];
    if (lane < 16) {
        part[wid][4 * lane + 0] = a0; part[wid][4 * lane + 1] = a1;
        part[wid][4 * lane + 2] = a2; part[wid][4 * lane + 3] = a3;
    }
    __syncthreads();
    if (tid < 64)
        q_part[blockIdx.x * 64 + tid] =
            (part[0][tid] + part[1][tid]) + (part[2][tid] + part[3][tid]);
}

// K1: K,V stream through a 3-deep raw LDS ring via global_load_lds with
// counted vmcnt (loads stay in flight across raw s_barrier). Raw slots are
// wave-private (wave DMAs + softmaxes its own 8 rows/chunk). bf16 staging +
// swizzle + MFMA structure unchanged from R2 (verified, 0 bank conflicts).
__global__ __launch_bounds__(512) void k1_stats(const float* __restrict__ K,
                                                const float* __restrict__ V,
                                                float* __restrict__ ctx_part) // [B1][4096]
{
    const int tid  = threadIdx.x;
    const int lane = tid & 63;
    const int wid  = tid >> 6;          // 8 waves
    const size_t base = (size_t)blockIdx.x * RPB;

    __shared__ float  rawK[3][4096];    // 48 KB: 3 slots x 64 rows x 64 cols fp32
    __shared__ float  rawV[3][4096];    // 48 KB
    __shared__ ushort kkT[2][4096];     // 16 KB: [buf][col][row] bf16, swizzled 16B granules
    __shared__ ushort vT [2][4096];     // 16 KB   (total 128 KB exactly)

    const int cb  = wid >> 1;           // ctx row-block (c)
    const int vb0 = (wid & 1) * 2;      // ctx col-blocks vb0, vb0+1
    f4v acc0 = {0.f, 0.f, 0.f, 0.f};
    f4v acc1 = {0.f, 0.f, 0.f, 0.f};

    const unsigned wr_off = (unsigned)lane * 128u + (unsigned)((wid ^ (lane & 7)) << 4);
    const int li = lane & 15, g = lane >> 4;
    const int lsrc = (lane >> 4) * 64 + (lane & 15) * 4;  // lane's float off in a 4-row group
    const int ldst = wid * 512;                           // wave's float region in a slot

#define ISSUE(ch) do { \
        const int _s = (ch) % 3; \
        const float* kb = K + (base + (size_t)(ch) * 64 + wid * 8) * 64; \
        const float* vb = V + (base + (size_t)(ch) * 64 + wid * 8) * 64; \
        dma16(kb + lsrc,       &rawK[_s][ldst]); \
        dma16(kb + 256 + lsrc, &rawK[_s][ldst + 256]); \
        dma16(vb + lsrc,       &rawV[_s][ldst]); \
        dma16(vb + 256 + lsrc, &rawV[_s][ldst + 256]); \
    } while (0)

    ISSUE(0); ISSUE(1); ISSUE(2);       // 12 DMA instrs in flight

#pragma unroll
    for (int ch = 0; ch < 8; ++ch) {
        // wait for chunk ch's 4 DMAs (newer chunks stay in flight)
        if (ch <= 5)      asm volatile("s_waitcnt vmcnt(8)" ::: "memory");
        else if (ch == 6) asm volatile("s_waitcnt vmcnt(4)" ::: "memory");
        else              asm volatile("s_waitcnt vmcnt(0)" ::: "memory");
        const int s = ch % 3, p = ch & 1;

        float kr[8], vr[8];
#pragma unroll
        for (int i = 0; i < 8; ++i) kr[i] = rawK[s][ldst + i * 64 + lane];
#pragma unroll
        for (int i = 0; i < 8; ++i) vr[i] = rawV[s][ldst + i * 64 + lane];

        float e[8], sm[8];
#pragma unroll
        for (int i = 0; i < 8; ++i) e[i] = exp2f(kr[i] * CL);   // bounded, no max
#pragma unroll
        for (int i = 0; i < 8; ++i) sm[i] = dpp_red16(e[i]);
#pragma unroll
        for (int i = 0; i < 8; ++i) sm[i] += __shfl_xor(sm[i], 16);
#pragma unroll
        for (int i = 0; i < 8; ++i) sm[i] += __shfl_xor(sm[i], 32);

        s8v kvp, vvp;
#pragma unroll
        for (int i = 0; i < 8; ++i) {
            kvp[i] = (short)f2bf(e[i] * __builtin_amdgcn_rcpf(sm[i]));
            vvp[i] = (short)f2bf(vr[i]);
        }
        *(s8v*)((char*)kkT[p] + wr_off) = kvp;
        *(s8v*)((char*)vT[p]  + wr_off) = vvp;
        asm volatile("s_waitcnt lgkmcnt(0)" ::: "memory");  // my ds writes+reads done
        if (ch < 5) ISSUE(ch + 3);                          // refill ring (slot ch%3 free)
        __builtin_amdgcn_s_barrier();                       // raw: vmcnt NOT drained
        asm volatile("" ::: "memory");

#pragma unroll
        for (int ks = 0; ks < 2; ++ks) {
            const int G  = ks * 4 + g;
            const int ca = cb  * 16 + li;
            const int c0 = vb0 * 16 + li;
            s8v a  = *(const s8v*)((const char*)kkT[p] + ca * 128 + ((G ^ (ca & 7)) << 4));
            s8v b0 = *(const s8v*)((const char*)vT[p]  + c0 * 128 + ((G ^ (c0 & 7)) << 4));
            s8v b1 = *(const s8v*)((const char*)vT[p]  + (c0 + 16) * 128 + ((G ^ (c0 & 7)) << 4));
            acc0 = __builtin_amdgcn_mfma_f32_16x16x32_bf16(a, b0, acc0, 0, 0, 0);
            acc1 = __builtin_amdgcn_mfma_f32_16x16x32_bf16(a, b1, acc1, 0, 0, 0);
        }
    }
#undef ISSUE
#pragma unroll
    for (int r = 0; r < 4; ++r) {
        const int row = cb * 16 + g * 4 + r;
        ctx_part[(size_t)blockIdx.x * 4096 + row * 64 + vb0 * 16 + li]       = acc0[r];
        ctx_part[(size_t)blockIdx.x * 4096 + row * 64 + (vb0 + 1) * 16 + li] = acc1[r];
    }
}

// K2: one block per column c. Reduce ctx partials AND Q column-sum partials,
// fold 1/colsum, emit ctx TRANSPOSED bf16: ctxfT[v][c].
__global__ __launch_bounds__(256) void k2(const float* __restrict__ ctx_part,
                                          const float* __restrict__ q_part,
                                          ushort* __restrict__ ctxfT) {
    const int c = blockIdx.x;        // 64 blocks
    const int tid = threadIdx.x;
    const int v = tid & 63;
    const int g = tid >> 6;          // 0..3
    __shared__ float red[4][64];
    __shared__ float qred[4][64];
    float s = 0.f;
    for (int b = g; b < B1; b += 4) s += ctx_part[(size_t)b * 4096 + c * 64 + v];
    float q = 0.f;
    for (int b = tid; b < B0; b += 256) q += q_part[b * 64 + c];
    red[g][v] = s;
    qred[g][v] = q;
    __syncthreads();
    if (tid < 64) {
        float t  = (red[0][v] + red[1][v]) + (red[2][v] + red[3][v]);
        float qv = (qred[0][v] + qred[1][v]) + (qred[2][v] + qred[3][v]);
        qv = dpp_red16(qv);
        qv += __shfl_xor(qv, 16);
        qv += __shfl_xor(qv, 32);
        ctxfT[v * 64 + c] = f2bf(t * __builtin_amdgcn_rcpf(qv));
    }
}

// K3: out[i][:] = exp2(Q[i][:]*CL) @ ctx'  via MFMA. A-frags straight from
// global Q (8 consecutive cols per lane); B-frags (ctx', 8KB) block-constant.
__global__ __launch_bounds__(256) void k3_out(const float* __restrict__ Q,
                                              const ushort* __restrict__ ctxfT,
                                              float* __restrict__ out) {
    const int tid  = threadIdx.x;
    const int lane = tid & 63;
    const int wid  = tid >> 6;      // 4 waves
    const int li = lane & 15, g = lane >> 4;

    s8v bfr[4][2];
#pragma unroll
    for (int vb = 0; vb < 4; ++vb)
#pragma unroll
        for (int ks = 0; ks < 2; ++ks)
            bfr[vb][ks] = *(const s8v*)((const char*)ctxfT +
                            2 * ((vb * 16 + li) * 64 + 32 * ks + 8 * g));

#pragma unroll
    for (int t = 0; t < 4; ++t) {   // fully unrolled: loads from all tiles in flight
        const int rb  = blockIdx.x * 256 + t * 64 + wid * 16;
        const int row = rb + li;
        const f4v* qp = (const f4v*)(Q + (size_t)row * 64);
        f4v q0 = qp[2 * g], q1 = qp[2 * g + 1];         // cols 8g..8g+7   (ks=0)
        f4v q2 = qp[8 + 2 * g], q3 = qp[8 + 2 * g + 1]; // cols 32+8g..+7  (ks=1)
        s8v a0, a1;
#pragma unroll
        for (int e = 0; e < 4; ++e) {
            a0[e]     = (short)f2bf(exp2f(q0[e] * CL));
            a0[e + 4] = (short)f2bf(exp2f(q1[e] * CL));
            a1[e]     = (short)f2bf(exp2f(q2[e] * CL));
            a1[e + 4] = (short)f2bf(exp2f(q3[e] * CL));
        }
#pragma unroll
        for (int vb = 0; vb < 4; ++vb) {
            f4v acc = {0.f, 0.f, 0.f, 0.f};
            acc = __builtin_amdgcn_mfma_f32_16x16x32_bf16(a0, bfr[vb][0], acc, 0, 0, 0);
            acc = __builtin_amdgcn_mfma_f32_16x16x32_bf16(a1, bfr[vb][1], acc, 0, 0, 0);
#pragma unroll
            for (int r = 0; r < 4; ++r)
                out[(size_t)(rb + g * 4 + r) * 64 + vb * 16 + li] = acc[r];
        }
    }
}

extern "C" void kernel_launch(void* const* d_in, const int* in_sizes, int n_in,
                              void* d_out, int out_size, void* d_ws, size_t ws_size,
                              hipStream_t stream) {
    const float* Q = (const float*)d_in[0];
    const float* K = (const float*)d_in[1];
    const float* V = (const float*)d_in[2];
    float* out = (float*)d_out;

    float* w = (float*)d_ws;
    size_t off = 0;
    float*  q_part = w + off;               off += (size_t)B0 * 64;
    ushort* ctxfT  = (ushort*)(w + off);    off += 2048;   // 4096 bf16 = 8KB
    float* ctx_part;
    const size_t need = (off + (size_t)B1 * 4096) * sizeof(float);
    if (ws_size >= need) {
        ctx_part = w + off;
    } else {
        // 8.4 MB of partials live in d_out scratch (k3 fully overwrites later)
        ctx_part = out;
    }

    k1_stats<<<B1, 512, 0, stream>>>(K, V, ctx_part);
    k0_qsum<<<B0, 256, 0, stream>>>(Q, q_part);
    k2<<<64, 256, 0, stream>>>(ctx_part, q_part, ctxfT);
    k3_out<<<NROWS / 256, 256, 0, stream>>>(Q, ctxfT, out);
}